// Round 3
// baseline (359.574 us; speedup 1.0000x reference)
//
#include <hip/hip_runtime.h>

#define THREADS 256

// ---------------- CSR build ----------------

__global__ void zero_kernel(int* __restrict__ p, int n) {
    int i = blockIdx.x * blockDim.x + threadIdx.x;
    if (i < n) p[i] = 0;
}

__global__ void hist_kernel(const int* __restrict__ row, int* __restrict__ cnt, int E) {
    int e = blockIdx.x * blockDim.x + threadIdx.x;
    if (e < E) atomicAdd(&cnt[row[e]], 1);
}

// single block, 1024 threads, n <= 16384
__global__ void scan_kernel(const int* __restrict__ cnt, int* __restrict__ rowptr,
                            int* __restrict__ nxt, int n) {
    __shared__ int sums[1024];
    const int t = threadIdx.x;
    const int base = t * 16;
    int local[16];
    int s = 0;
#pragma unroll
    for (int i = 0; i < 16; ++i) {
        int idx = base + i;
        int v = (idx < n) ? cnt[idx] : 0;
        local[i] = v;
        s += v;
    }
    sums[t] = s;
    __syncthreads();
    for (int off = 1; off < 1024; off <<= 1) {
        int v = (t >= off) ? sums[t - off] : 0;
        __syncthreads();
        sums[t] += v;
        __syncthreads();
    }
    int run = (t == 0) ? 0 : sums[t - 1];
#pragma unroll
    for (int i = 0; i < 16; ++i) {
        int idx = base + i;
        if (idx < n) {
            rowptr[idx] = run;
            nxt[idx] = run;
            run += local[i];
        }
    }
    if (t == 1023) rowptr[n] = sums[1023];
}

__global__ void scatter_kernel(const int* __restrict__ row, const int* __restrict__ col,
                               const float* __restrict__ val, int* __restrict__ nxt,
                               int* __restrict__ cols_s, float* __restrict__ vals_s, int E) {
    int e = blockIdx.x * blockDim.x + threadIdx.x;
    if (e < E) {
        int p = atomicAdd(&nxt[row[e]], 1);
        cols_s[p] = col[e];
        vals_s[p] = val[e];
    }
}

// ---------------- GEMMs ----------------

// X[n x K] @ W[K x 32] -> Y[n x 32]; thread = (row, f)
__global__ void gemm0_kernel(const float* __restrict__ X, const float* __restrict__ W,
                             float* __restrict__ Y, int n, int K) {
    int idx = blockIdx.x * blockDim.x + threadIdx.x;
    int r = idx >> 5;
    int f = idx & 31;
    if (r >= n) return;
    const float* xr = X + (size_t)r * K;
    float acc = 0.f;
#pragma unroll 8
    for (int k = 0; k < K; ++k) acc = fmaf(xr[k], W[k * 32 + f], acc);
    Y[r * 32 + f] = acc;
}

// X[n x 32] @ W[32 x FD] -> Y[n x FD]; W staged in LDS
template <int FD>
__global__ void gemm32_kernel(const float* __restrict__ X, const float* __restrict__ W,
                              float* __restrict__ Y, int n) {
    __shared__ float w[32 * FD];
    const int t = threadIdx.x;
    for (int i = t; i < 32 * FD; i += THREADS) w[i] = W[i];
    __syncthreads();
    int idx = blockIdx.x * THREADS + t;
    int r = idx / FD;
    int f = idx % FD;
    if (r >= n) return;
    const float* xr = X + (size_t)r * 32;
    float acc = 0.f;
#pragma unroll
    for (int k = 0; k < 32; ++k) acc = fmaf(xr[k], w[k * FD + f], acc);
    Y[r * FD + f] = acc;
}

// ---------------- SpMM (CSR, one 32-lane group per row) ----------------

template <int F, bool RELU>
__global__ void spmm_kernel(const int* __restrict__ rowptr, const int* __restrict__ cols,
                            const float* __restrict__ vals, const float* __restrict__ Y,
                            float* __restrict__ H, int n) {
    int g = (blockIdx.x * THREADS + threadIdx.x) >> 5;  // 32-lane group = row
    if (g >= n) return;
    int f = threadIdx.x & (F - 1);
    int s = rowptr[g];
    int e = rowptr[g + 1];
    float acc = 0.f;
    for (int i = s; i < e; ++i) {
        acc = fmaf(vals[i], Y[(size_t)cols[i] * F + f], acc);
    }
    if (RELU) acc = fmaxf(acc, 0.f);
    H[(size_t)g * F + f] = acc;
}

// ---------------- z @ z^T ----------------

// block: 256 threads -> 16 rows x 1024 cols tile. zi in LDS, 4 j-rows in regs.
__global__ void zzt_kernel(const float* __restrict__ z, float* __restrict__ out, int n) {
    __shared__ float zi[16][16];
    const int t = threadIdx.x;
    const int bi = blockIdx.y * 16;
    {
        int r = t >> 4, c = t & 15;
        zi[r][c] = (bi + r < n) ? z[(size_t)(bi + r) * 16 + c] : 0.f;
    }
    __syncthreads();
    int j0 = blockIdx.x * 1024 + t * 4;
    if (j0 >= n) return;
    float zj[4][16];
#pragma unroll
    for (int jj = 0; jj < 4; ++jj) {
#pragma unroll
        for (int k = 0; k < 16; k += 4) {
            float4 v = *reinterpret_cast<const float4*>(z + (size_t)(j0 + jj) * 16 + k);
            zj[jj][k] = v.x; zj[jj][k + 1] = v.y; zj[jj][k + 2] = v.z; zj[jj][k + 3] = v.w;
        }
    }
#pragma unroll
    for (int i = 0; i < 16; ++i) {
        if (bi + i >= n) break;
        float4 o = {0.f, 0.f, 0.f, 0.f};
#pragma unroll
        for (int k = 0; k < 16; ++k) {
            float a = zi[i][k];
            o.x = fmaf(a, zj[0][k], o.x);
            o.y = fmaf(a, zj[1][k], o.y);
            o.z = fmaf(a, zj[2][k], o.z);
            o.w = fmaf(a, zj[3][k], o.w);
        }
        *reinterpret_cast<float4*>(out + (size_t)(bi + i) * n + j0) = o;
    }
}

// ---------------- launch ----------------

extern "C" void kernel_launch(void* const* d_in, const int* in_sizes, int n_in,
                              void* d_out, int out_size, void* d_ws, size_t ws_size,
                              hipStream_t stream) {
    const float* features = (const float*)d_in[0];
    const int*   adj_row  = (const int*)d_in[1];
    const int*   adj_col  = (const int*)d_in[2];
    const float* adj_vals = (const float*)d_in[3];
    const float* W0 = (const float*)d_in[4];
    const float* Wh[5] = {(const float*)d_in[5], (const float*)d_in[6], (const float*)d_in[7],
                          (const float*)d_in[8], (const float*)d_in[9]};
    const float* W6 = (const float*)d_in[10];

    const int E = in_sizes[1];
    const int K = in_sizes[4] / 32;   // 512
    const int N = in_sizes[0] / K;    // 10000

    char* ws = (char*)d_ws;
    size_t off = 0;
    auto alloc = [&](size_t bytes) -> void* {
        void* p = ws + off;
        off = (off + bytes + 255) & ~(size_t)255;
        return p;
    };
    int*   rowptr = (int*)alloc((size_t)(N + 1) * 4);
    int*   nxt    = (int*)alloc((size_t)N * 4);
    int*   cnt    = (int*)alloc((size_t)N * 4);
    int*   cols_s = (int*)alloc((size_t)E * 4);
    float* vals_s = (float*)alloc((size_t)E * 4);
    float* Ybuf   = (float*)alloc((size_t)N * 32 * 4);
    float* Ha     = (float*)alloc((size_t)N * 32 * 4);
    float* Hb     = (float*)alloc((size_t)N * 32 * 4);
    float* zbuf   = (float*)alloc((size_t)N * 16 * 4);

    const int gridE = (E + THREADS - 1) / THREADS;
    // one 32-lane group per row -> N*32 threads total
    const int gridRow = (N * 32 + THREADS - 1) / THREADS;

    // zero cnt with a normal compute dispatch (graph memset node was ~233us!)
    zero_kernel<<<(N + THREADS - 1) / THREADS, THREADS, 0, stream>>>(cnt, N);
    hist_kernel<<<gridE, THREADS, 0, stream>>>(adj_row, cnt, E);
    scan_kernel<<<1, 1024, 0, stream>>>(cnt, rowptr, nxt, N);
    scatter_kernel<<<gridE, THREADS, 0, stream>>>(adj_row, adj_col, adj_vals, nxt, cols_s, vals_s, E);

    // layer 0: features @ W0 -> Y; spmm+relu -> Ha
    gemm0_kernel<<<(N * 32 + THREADS - 1) / THREADS, THREADS, 0, stream>>>(features, W0, Ybuf, N, K);
    spmm_kernel<32, true><<<gridRow, THREADS, 0, stream>>>(rowptr, cols_s, vals_s, Ybuf, Ha, N);

    float* hin = Ha;
    float* hout = Hb;
    for (int l = 0; l < 5; ++l) {
        gemm32_kernel<32><<<(N * 32 + THREADS - 1) / THREADS, THREADS, 0, stream>>>(hin, Wh[l], Ybuf, N);
        spmm_kernel<32, true><<<gridRow, THREADS, 0, stream>>>(rowptr, cols_s, vals_s, Ybuf, hout, N);
        float* tmp = hin; hin = hout; hout = tmp;
    }

    // z layer: hin @ W6 (32->16) -> Y; spmm (no relu) -> z
    gemm32_kernel<16><<<(N * 16 + THREADS - 1) / THREADS, THREADS, 0, stream>>>(hin, W6, Ybuf, N);
    spmm_kernel<16, false><<<gridRow, THREADS, 0, stream>>>(rowptr, cols_s, vals_s, Ybuf, zbuf, N);

    // recon = z @ z^T
    dim3 zg((N + 1023) / 1024, (N + 15) / 16);
    zzt_kernel<<<zg, THREADS, 0, stream>>>(zbuf, (float*)d_out, N);
}

// Round 5
// 336.543 us; speedup vs baseline: 1.0684x; 1.0684x over previous
//
#include <hip/hip_runtime.h>

#define THREADS 256

typedef float floatx4 __attribute__((ext_vector_type(4)));

// ---------------- CSR build ----------------

__global__ void zero_kernel(int* __restrict__ p, int n) {
    int i = blockIdx.x * blockDim.x + threadIdx.x;
    if (i < n) p[i] = 0;
}

__global__ void hist_kernel(const int* __restrict__ row, int* __restrict__ cnt, int E) {
    int e = blockIdx.x * blockDim.x + threadIdx.x;
    if (e < E) atomicAdd(&cnt[row[e]], 1);
}

// single block, 1024 threads, n <= 16384
__global__ void scan_kernel(const int* __restrict__ cnt, int* __restrict__ rowptr,
                            int* __restrict__ nxt, int n) {
    __shared__ int sums[1024];
    const int t = threadIdx.x;
    const int base = t * 16;
    int local[16];
    int s = 0;
#pragma unroll
    for (int i = 0; i < 16; ++i) {
        int idx = base + i;
        int v = (idx < n) ? cnt[idx] : 0;
        local[i] = v;
        s += v;
    }
    sums[t] = s;
    __syncthreads();
    for (int off = 1; off < 1024; off <<= 1) {
        int v = (t >= off) ? sums[t - off] : 0;
        __syncthreads();
        sums[t] += v;
        __syncthreads();
    }
    int run = (t == 0) ? 0 : sums[t - 1];
#pragma unroll
    for (int i = 0; i < 16; ++i) {
        int idx = base + i;
        if (idx < n) {
            rowptr[idx] = run;
            nxt[idx] = run;
            run += local[i];
        }
    }
    if (t == 1023) rowptr[n] = sums[1023];
}

__global__ void scatter_kernel(const int* __restrict__ row, const int* __restrict__ col,
                               const float* __restrict__ val, int* __restrict__ nxt,
                               int* __restrict__ cols_s, float* __restrict__ vals_s, int E) {
    int e = blockIdx.x * blockDim.x + threadIdx.x;
    if (e < E) {
        int p = atomicAdd(&nxt[row[e]], 1);
        cols_s[p] = col[e];
        vals_s[p] = val[e];
    }
}

// ---------------- dense input GEMM ----------------

// X[n x K] @ W[K x 32] -> Y[n x 32]; 32 lanes per row, lane = out feature
__global__ void gemm0_kernel(const float* __restrict__ X, const float* __restrict__ W,
                             float* __restrict__ Y, int n, int K) {
    int idx = blockIdx.x * blockDim.x + threadIdx.x;
    int r = idx >> 5;
    int f = idx & 31;
    if (r >= n) return;
    const float* xr = X + (size_t)r * K;
    float acc = 0.f;
#pragma unroll 8
    for (int k = 0; k < K; ++k) acc = fmaf(xr[k], W[k * 32 + f], acc);
    Y[r * 32 + f] = acc;
}

// ---------------- fused SpMM(+relu) + 32xFOUT GEMM ----------------
// Computes: Yout[r, :] = relu( sum_e vals[e] * Yin[col[e], :] ) @ W
// One 32-lane group per row; h[k] lives in lane k; gemm via shfl broadcast.
template <int FOUT>
__global__ void fused_spmm_gemm_kernel(const int* __restrict__ rowptr, const int* __restrict__ cols,
                                       const float* __restrict__ vals, const float* __restrict__ Yin,
                                       const float* __restrict__ W, float* __restrict__ Yout, int n) {
    __shared__ float w[32 * FOUT];
    const int t = threadIdx.x;
    for (int i = t; i < 32 * FOUT; i += THREADS) w[i] = W[i];
    __syncthreads();

    int g = (blockIdx.x * THREADS + t) >> 5;  // row
    if (g >= n) return;
    int f = t & 31;
    int s = rowptr[g];
    int e = rowptr[g + 1];
    float acc = 0.f;
    for (int i = s; i < e; ++i) {
        acc = fmaf(vals[i], Yin[(size_t)cols[i] * 32 + f], acc);
    }
    float h = fmaxf(acc, 0.f);

    const int fo = f & (FOUT - 1);
    float y = 0.f;
#pragma unroll
    for (int k = 0; k < 32; ++k) {
        y = fmaf(__shfl(h, k, 32), w[k * FOUT + fo], y);
    }
    if (f < FOUT) Yout[(size_t)g * FOUT + f] = y;
}

// plain SpMM, no relu, F=16 (final z layer)
__global__ void spmm16_kernel(const int* __restrict__ rowptr, const int* __restrict__ cols,
                              const float* __restrict__ vals, const float* __restrict__ Yin,
                              float* __restrict__ Z, int n) {
    int g = (blockIdx.x * THREADS + threadIdx.x) >> 5;
    if (g >= n) return;
    int f = threadIdx.x & 15;
    int lane = threadIdx.x & 31;
    int s = rowptr[g];
    int e = rowptr[g + 1];
    float acc = 0.f;
    for (int i = s; i < e; ++i) {
        acc = fmaf(vals[i], Yin[(size_t)cols[i] * 16 + f], acc);
    }
    if (lane < 16) Z[(size_t)g * 16 + f] = acc;
}

// ---------------- z @ z^T ----------------

// block: 256 threads -> 32 rows x 1024 cols tile. zi in LDS, 4 j-rows in regs,
// nontemporal floatx4 stores (pure write stream, don't pollute L2).
__global__ void zzt_kernel(const float* __restrict__ z, float* __restrict__ out, int n) {
    __shared__ float zi[32][16];
    const int t = threadIdx.x;
    const int bi = blockIdx.y * 32;
    for (int i = t; i < 512; i += THREADS) {
        int r = i >> 4, c = i & 15;
        zi[r][c] = (bi + r < n) ? z[(size_t)(bi + r) * 16 + c] : 0.f;
    }
    __syncthreads();
    int j0 = blockIdx.x * 1024 + t * 4;
    if (j0 >= n) return;
    float zj[4][16];
#pragma unroll
    for (int jj = 0; jj < 4; ++jj) {
#pragma unroll
        for (int k = 0; k < 16; k += 4) {
            floatx4 v = *reinterpret_cast<const floatx4*>(z + (size_t)(j0 + jj) * 16 + k);
            zj[jj][k] = v.x; zj[jj][k + 1] = v.y; zj[jj][k + 2] = v.z; zj[jj][k + 3] = v.w;
        }
    }
#pragma unroll 4
    for (int i = 0; i < 32; ++i) {
        if (bi + i >= n) break;
        floatx4 o = {0.f, 0.f, 0.f, 0.f};
#pragma unroll
        for (int k = 0; k < 16; ++k) {
            float a = zi[i][k];
            o.x = fmaf(a, zj[0][k], o.x);
            o.y = fmaf(a, zj[1][k], o.y);
            o.z = fmaf(a, zj[2][k], o.z);
            o.w = fmaf(a, zj[3][k], o.w);
        }
        __builtin_nontemporal_store(o, reinterpret_cast<floatx4*>(out + (size_t)(bi + i) * n + j0));
    }
}

// ---------------- launch ----------------

extern "C" void kernel_launch(void* const* d_in, const int* in_sizes, int n_in,
                              void* d_out, int out_size, void* d_ws, size_t ws_size,
                              hipStream_t stream) {
    const float* features = (const float*)d_in[0];
    const int*   adj_row  = (const int*)d_in[1];
    const int*   adj_col  = (const int*)d_in[2];
    const float* adj_vals = (const float*)d_in[3];
    const float* W0 = (const float*)d_in[4];
    const float* Wh[5] = {(const float*)d_in[5], (const float*)d_in[6], (const float*)d_in[7],
                          (const float*)d_in[8], (const float*)d_in[9]};
    const float* W6 = (const float*)d_in[10];

    const int E = in_sizes[1];
    const int K = in_sizes[4] / 32;   // 512
    const int N = in_sizes[0] / K;    // 10000

    char* ws = (char*)d_ws;
    size_t off = 0;
    auto alloc = [&](size_t bytes) -> void* {
        void* p = ws + off;
        off = (off + bytes + 255) & ~(size_t)255;
        return p;
    };
    int*   rowptr = (int*)alloc((size_t)(N + 1) * 4);
    int*   nxt    = (int*)alloc((size_t)N * 4);
    int*   cnt    = (int*)alloc((size_t)N * 4);
    int*   cols_s = (int*)alloc((size_t)E * 4);
    float* vals_s = (float*)alloc((size_t)E * 4);
    float* Ya     = (float*)alloc((size_t)N * 32 * 4);
    float* Yb     = (float*)alloc((size_t)N * 32 * 4);
    float* Y16    = (float*)alloc((size_t)N * 16 * 4);
    float* zbuf   = (float*)alloc((size_t)N * 16 * 4);

    const int gridE = (E + THREADS - 1) / THREADS;
    const int gridRow = (N * 32 + THREADS - 1) / THREADS;  // one 32-lane group per row

    zero_kernel<<<(N + THREADS - 1) / THREADS, THREADS, 0, stream>>>(cnt, N);
    hist_kernel<<<gridE, THREADS, 0, stream>>>(adj_row, cnt, E);
    scan_kernel<<<1, 1024, 0, stream>>>(cnt, rowptr, nxt, N);
    scatter_kernel<<<gridE, THREADS, 0, stream>>>(adj_row, adj_col, adj_vals, nxt, cols_s, vals_s, E);

    // Y0 = X @ W0
    gemm0_kernel<<<gridRow, THREADS, 0, stream>>>(features, W0, Ya, N, K);

    // 5 hidden layers: Y_{l+1} = relu(A @ Y_l) @ W_{l+1}
    float* yin = Ya;
    float* yout = Yb;
    for (int l = 0; l < 5; ++l) {
        fused_spmm_gemm_kernel<32><<<gridRow, THREADS, 0, stream>>>(rowptr, cols_s, vals_s, yin, Wh[l], yout, N);
        float* tmp = yin; yin = yout; yout = tmp;
    }
    // Y6 = relu(A @ Y5) @ W6  (32 -> 16)
    fused_spmm_gemm_kernel<16><<<gridRow, THREADS, 0, stream>>>(rowptr, cols_s, vals_s, yin, W6, Y16, N);
    // z = A @ Y6 (no relu)
    spmm16_kernel<<<gridRow, THREADS, 0, stream>>>(rowptr, cols_s, vals_s, Y16, zbuf, N);

    // recon = z @ z^T
    dim3 zg((N + 1023) / 1024, (N + 31) / 32);
    zzt_kernel<<<zg, THREADS, 0, stream>>>(zbuf, (float*)d_out, N);
}